// Round 6
// baseline (172.495 us; speedup 1.0000x reference)
//
#include <hip/hip_runtime.h>

// mrnLoss: out = sum((w_preds - w_stars)^2) + N - sum_n( y_n * <feats_n, w_preds[seg_n]> )
// C=1000, D=512, N=200000. Memory-bound: ~416 MB total read -> ~66us floor @6.3TB/s.
//
// R6 changes vs R5 (81.8us) / R4 (78.7us, best):
//  - revert R5's NT-wst load (back to R4 loop body, byte-for-byte)
//  - kill the final_reduce kernel node: per-block partials in d_ws + device-scope
//    arrival counter (zeroed by a 4-byte memset node each call); the LAST
//    finishing block reduces the 1024 partials and plain-stores
//    out[0] = N + total. One kernel node total, no same-address atomic drain.

#define BLOCK 256
#define GRID  1024
#define CHUNK 49
#define NWAVES (GRID * (BLOCK / 64))   // 4096 waves

typedef float vf4 __attribute__((ext_vector_type(4)));

__global__ void init_out(float* out, float n_const) { out[0] = n_const; }

__device__ __forceinline__ float dot8(vf4 a0, vf4 a1, vf4 u0, vf4 u1) {
    return a0.x * u0.x + a0.y * u0.y + a0.z * u0.z + a0.w * u0.w
         + a1.x * u1.x + a1.y * u1.y + a1.z * u1.z + a1.w * u1.w;
}

__global__ __launch_bounds__(BLOCK, 4) void mrn_loss_kernel(
    const float* __restrict__ wp,   // (C, D) = (1000, 512)
    const float* __restrict__ wst,  // (C, D)
    const float* __restrict__ feats,// (N, D)
    const float* __restrict__ ys,   // (N,)
    const int*   __restrict__ seg,  // (N,)
    float* __restrict__ part,       // d_ws: GRID partials (or null -> atomic fallback)
    unsigned* __restrict__ counter, // d_ws + GRID*4: arrival counter (pre-zeroed)
    float* __restrict__ out,
    int N)
{
    const int tid      = blockIdx.x * BLOCK + threadIdx.x;
    const int nthreads = GRID * BLOCK;

    float acc_a = 0.0f;
    float acc_b = 0.0f;

    // ---- Part 1: reg_loss = sum((wp - wst)^2); warms wp into every XCD L2.
    {
        const int REG4 = (1000 * 512) / 4;
        const vf4* wp4 = (const vf4*)wp;
        const vf4* ws4 = (const vf4*)wst;
        for (int i = tid; i < REG4; i += nthreads) {
            vf4 a = wp4[i];
            vf4 b = ws4[i];
            vf4 d = a - b;
            acc_a += d.x * d.x + d.y * d.y + d.z * d.z + d.w * d.w;
        }
    }

    // ---- Part 2: -sum_n y_n * <feats_n, wp[seg_n]>
    // One wave per CHUNK=49 consecutive samples (98KB contiguous feats stream).
    {
        const int lane = threadIdx.x & 63;
        const int wave = __builtin_amdgcn_readfirstlane(tid >> 6);

        for (int base = wave * CHUNK; base < N; base += NWAVES * CHUNK) {
            const int cnt = min(CHUNK, N - base);

            // Coalesced preload of this chunk's seg/ys (one transaction each).
            int   myseg = 0;
            float myy   = 0.0f;
            if (lane < cnt) {
                myseg = seg[base + lane];
                myy   = ys[base + lane];
            }

            const vf4* f4 = (const vf4*)feats + (size_t)base * 128;

            if (cnt == CHUNK) {
                #pragma unroll 3
                for (int j = 0; j < CHUNK; ++j) {
                    const int   c = __builtin_amdgcn_readlane(myseg, j);
                    const float y = __int_as_float(
                        __builtin_amdgcn_readlane(__float_as_int(myy), j));

                    const vf4* fr = f4 + (size_t)j * 128;
                    const vf4* wr = (const vf4*)(wp + (size_t)c * 512);

                    vf4 a0 = __builtin_nontemporal_load(fr + lane);
                    vf4 a1 = __builtin_nontemporal_load(fr + lane + 64);
                    vf4 u0 = wr[lane];
                    vf4 u1 = wr[lane + 64];

                    const float d = dot8(a0, a1, u0, u1);
                    if (j & 1) acc_b -= y * d;
                    else       acc_a -= y * d;
                }
            } else {
                for (int j = 0; j < cnt; ++j) {
                    const int   c = __builtin_amdgcn_readlane(myseg, j);
                    const float y = __int_as_float(
                        __builtin_amdgcn_readlane(__float_as_int(myy), j));
                    const vf4* fr = f4 + (size_t)j * 128;
                    const vf4* wr = (const vf4*)(wp + (size_t)c * 512);
                    vf4 a0 = __builtin_nontemporal_load(fr + lane);
                    vf4 a1 = __builtin_nontemporal_load(fr + lane + 64);
                    vf4 u0 = wr[lane];
                    vf4 u1 = wr[lane + 64];
                    acc_a -= y * dot8(a0, a1, u0, u1);
                }
            }
        }
    }

    // ---- Block reduce: shuffle within wave, LDS across waves.
    float acc = acc_a + acc_b;
    for (int off = 32; off > 0; off >>= 1)
        acc += __shfl_down(acc, off, 64);

    __shared__ float sacc[BLOCK / 64];
    __shared__ int   is_last;
    const int lane = threadIdx.x & 63;
    const int wid  = threadIdx.x >> 6;
    if (lane == 0) sacc[wid] = acc;
    __syncthreads();

    if (part == nullptr) {
        // Fallback path: out pre-initialized to N by init_out; atomic accumulate.
        if (threadIdx.x == 0)
            atomicAdd(out, sacc[0] + sacc[1] + sacc[2] + sacc[3]);
        return;
    }

    if (threadIdx.x == 0) {
        const float b = sacc[0] + sacc[1] + sacc[2] + sacc[3];
        __hip_atomic_store(&part[blockIdx.x], b, __ATOMIC_RELEASE,
                           __HIP_MEMORY_SCOPE_AGENT);
        const unsigned old = __hip_atomic_fetch_add(counter, 1u, __ATOMIC_ACQ_REL,
                                                    __HIP_MEMORY_SCOPE_AGENT);
        is_last = (old == GRID - 1) ? 1 : 0;
    }
    __syncthreads();

    // ---- Last-finishing block: reduce the GRID partials, single plain store.
    if (is_last) {
        float a = 0.0f;
        for (int i = threadIdx.x; i < GRID; i += BLOCK)
            a += __hip_atomic_load(&part[i], __ATOMIC_ACQUIRE,
                                   __HIP_MEMORY_SCOPE_AGENT);
        for (int off = 32; off > 0; off >>= 1)
            a += __shfl_down(a, off, 64);
        if (lane == 0) sacc[wid] = a;
        __syncthreads();
        if (threadIdx.x == 0)
            out[0] = (float)N + sacc[0] + sacc[1] + sacc[2] + sacc[3];
    }
}

extern "C" void kernel_launch(void* const* d_in, const int* in_sizes, int n_in,
                              void* d_out, int out_size, void* d_ws, size_t ws_size,
                              hipStream_t stream) {
    const float* wp    = (const float*)d_in[0];
    const float* wst   = (const float*)d_in[1];
    const float* feats = (const float*)d_in[2];
    const float* ys    = (const float*)d_in[3];
    const int*   seg   = (const int*)d_in[4];
    float* out = (float*)d_out;

    const int N = in_sizes[3];   // 200000 samples

    if (ws_size >= (GRID + 1) * sizeof(float)) {
        float*    part    = (float*)d_ws;
        unsigned* counter = (unsigned*)((char*)d_ws + GRID * sizeof(float));
        // 4-byte memset node: deterministic arrival count every call.
        hipMemsetAsync(counter, 0, sizeof(unsigned), stream);
        mrn_loss_kernel<<<GRID, BLOCK, 0, stream>>>(wp, wst, feats, ys, seg,
                                                    part, counter, out, N);
    } else {
        init_out<<<1, 1, 0, stream>>>(out, (float)N);
        mrn_loss_kernel<<<GRID, BLOCK, 0, stream>>>(wp, wst, feats, ys, seg,
                                                    nullptr, nullptr, out, N);
    }
}

// Round 7
// 84.162 us; speedup vs baseline: 2.0496x; 2.0496x over previous
//
#include <hip/hip_runtime.h>

// mrnLoss: out = sum((w_preds - w_stars)^2) + N - sum_n( y_n * <feats_n, w_preds[seg_n]> )
// C=1000, D=512, N=200000. Memory-bound: ~416 MB total read -> ~63us floor.
//
// R7 = R4 structure (78.7us best; R6's agent-scope-fence single-pass reduction
// caused an L2 writeback/invalidate storm -> 172us, reverted) with ONE change:
//  - drop the non-temporal hint on feats loads (never A/B'd; NT bypasses TCC
//    read path optimizations; feats is read-once so L2 reuse doesn't matter,
//    testing whether plain cached loads stream faster)

#define BLOCK 256
#define GRID  1024
#define CHUNK 49
#define NWAVES (GRID * (BLOCK / 64))   // 4096 waves

typedef float vf4 __attribute__((ext_vector_type(4)));

__global__ void init_out(float* out, float n_const) { out[0] = n_const; }

__global__ void final_reduce(const float* __restrict__ part, float* __restrict__ out,
                             float n_const) {
    // 256 threads reduce GRID=1024 partials.
    float a = 0.0f;
    for (int i = threadIdx.x; i < GRID; i += 256) a += part[i];
    for (int off = 32; off > 0; off >>= 1) a += __shfl_down(a, off, 64);
    __shared__ float s[4];
    if ((threadIdx.x & 63) == 0) s[threadIdx.x >> 6] = a;
    __syncthreads();
    if (threadIdx.x == 0) out[0] = n_const + s[0] + s[1] + s[2] + s[3];
}

__device__ __forceinline__ float dot8(vf4 a0, vf4 a1, vf4 u0, vf4 u1) {
    return a0.x * u0.x + a0.y * u0.y + a0.z * u0.z + a0.w * u0.w
         + a1.x * u1.x + a1.y * u1.y + a1.z * u1.z + a1.w * u1.w;
}

__global__ __launch_bounds__(BLOCK, 4) void mrn_loss_kernel(
    const float* __restrict__ wp,   // (C, D) = (1000, 512)
    const float* __restrict__ wst,  // (C, D)
    const float* __restrict__ feats,// (N, D)
    const float* __restrict__ ys,   // (N,)
    const int*   __restrict__ seg,  // (N,)
    float* __restrict__ blockout,   // per-block partials (d_ws) or null
    float* __restrict__ out,        // atomic fallback target
    int N)
{
    const int tid      = blockIdx.x * BLOCK + threadIdx.x;
    const int nthreads = GRID * BLOCK;

    float acc_a = 0.0f;
    float acc_b = 0.0f;

    // ---- Part 1: reg_loss = sum((wp - wst)^2); warms wp into every XCD L2.
    {
        const int REG4 = (1000 * 512) / 4;
        const vf4* wp4 = (const vf4*)wp;
        const vf4* ws4 = (const vf4*)wst;
        for (int i = tid; i < REG4; i += nthreads) {
            vf4 a = wp4[i];
            vf4 b = ws4[i];
            vf4 d = a - b;
            acc_a += d.x * d.x + d.y * d.y + d.z * d.z + d.w * d.w;
        }
    }

    // ---- Part 2: -sum_n y_n * <feats_n, wp[seg_n]>
    // One wave per CHUNK=49 consecutive samples (98KB contiguous feats stream).
    {
        const int lane = threadIdx.x & 63;
        const int wave = __builtin_amdgcn_readfirstlane(tid >> 6);

        for (int base = wave * CHUNK; base < N; base += NWAVES * CHUNK) {
            const int cnt = min(CHUNK, N - base);

            // Coalesced preload of this chunk's seg/ys (one transaction each).
            int   myseg = 0;
            float myy   = 0.0f;
            if (lane < cnt) {
                myseg = seg[base + lane];
                myy   = ys[base + lane];
            }

            const vf4* f4 = (const vf4*)feats + (size_t)base * 128;

            if (cnt == CHUNK) {
                #pragma unroll 3
                for (int j = 0; j < CHUNK; ++j) {
                    const int   c = __builtin_amdgcn_readlane(myseg, j);
                    const float y = __int_as_float(
                        __builtin_amdgcn_readlane(__float_as_int(myy), j));

                    const vf4* fr = f4 + (size_t)j * 128;
                    const vf4* wr = (const vf4*)(wp + (size_t)c * 512);

                    vf4 a0 = fr[lane];
                    vf4 a1 = fr[lane + 64];
                    vf4 u0 = wr[lane];
                    vf4 u1 = wr[lane + 64];

                    const float d = dot8(a0, a1, u0, u1);
                    if (j & 1) acc_b -= y * d;
                    else       acc_a -= y * d;
                }
            } else {
                for (int j = 0; j < cnt; ++j) {
                    const int   c = __builtin_amdgcn_readlane(myseg, j);
                    const float y = __int_as_float(
                        __builtin_amdgcn_readlane(__float_as_int(myy), j));
                    const vf4* fr = f4 + (size_t)j * 128;
                    const vf4* wr = (const vf4*)(wp + (size_t)c * 512);
                    vf4 a0 = fr[lane];
                    vf4 a1 = fr[lane + 64];
                    vf4 u0 = wr[lane];
                    vf4 u1 = wr[lane + 64];
                    acc_a -= y * dot8(a0, a1, u0, u1);
                }
            }
        }
    }

    // ---- Reduce: shuffle within wave, LDS across waves, one store per block.
    float acc = acc_a + acc_b;
    for (int off = 32; off > 0; off >>= 1)
        acc += __shfl_down(acc, off, 64);

    __shared__ float sacc[BLOCK / 64];
    const int lane = threadIdx.x & 63;
    const int wid  = threadIdx.x >> 6;
    if (lane == 0) sacc[wid] = acc;
    __syncthreads();

    if (threadIdx.x == 0) {
        float b = sacc[0] + sacc[1] + sacc[2] + sacc[3];
        if (blockout) blockout[blockIdx.x] = b;
        else          atomicAdd(out, b);
    }
}

extern "C" void kernel_launch(void* const* d_in, const int* in_sizes, int n_in,
                              void* d_out, int out_size, void* d_ws, size_t ws_size,
                              hipStream_t stream) {
    const float* wp    = (const float*)d_in[0];
    const float* wst   = (const float*)d_in[1];
    const float* feats = (const float*)d_in[2];
    const float* ys    = (const float*)d_in[3];
    const int*   seg   = (const int*)d_in[4];
    float* out = (float*)d_out;

    const int N = in_sizes[3];   // 200000 samples

    if (ws_size >= GRID * sizeof(float)) {
        float* part = (float*)d_ws;
        mrn_loss_kernel<<<GRID, BLOCK, 0, stream>>>(wp, wst, feats, ys, seg,
                                                    part, nullptr, N);
        final_reduce<<<1, 256, 0, stream>>>(part, out, (float)N);
    } else {
        init_out<<<1, 1, 0, stream>>>(out, (float)N);
        mrn_loss_kernel<<<GRID, BLOCK, 0, stream>>>(wp, wst, feats, ys, seg,
                                                    nullptr, out, N);
    }
}

// Round 8
// 78.761 us; speedup vs baseline: 2.1901x; 1.0686x over previous
//
#include <hip/hip_runtime.h>

// mrnLoss: out = sum((w_preds - w_stars)^2) + N - sum_n( y_n * <feats_n, w_preds[seg_n]> )
// C=1000, D=512, N=200000. Memory-bound: ~416 MB total read -> ~63us floor.
//
// R8 = R4 verbatim (session best, 78.7us). Ablation ledger:
//  - NT on feats: +5.5us (R7 proved removal hurts: protects wp's L2 residency)
//  - NT on wst / memset+1024-atomic finish: -3us (R5, rejected)
//  - agent-scope last-block reduction: -94us, L2 wb/inv storm (R6, rejected)
//  - main kernel ~5.6 TB/s effective on 416 MB mixed stream+gather ~= 89% of
//    this chip's measured fill ceiling -> practical roofline.

#define BLOCK 256
#define GRID  1024
#define CHUNK 49
#define NWAVES (GRID * (BLOCK / 64))   // 4096 waves

typedef float vf4 __attribute__((ext_vector_type(4)));

__global__ void init_out(float* out, float n_const) { out[0] = n_const; }

__global__ void final_reduce(const float* __restrict__ part, float* __restrict__ out,
                             float n_const) {
    // 256 threads reduce GRID=1024 partials.
    float a = 0.0f;
    for (int i = threadIdx.x; i < GRID; i += 256) a += part[i];
    for (int off = 32; off > 0; off >>= 1) a += __shfl_down(a, off, 64);
    __shared__ float s[4];
    if ((threadIdx.x & 63) == 0) s[threadIdx.x >> 6] = a;
    __syncthreads();
    if (threadIdx.x == 0) out[0] = n_const + s[0] + s[1] + s[2] + s[3];
}

__device__ __forceinline__ float dot8(vf4 a0, vf4 a1, vf4 u0, vf4 u1) {
    return a0.x * u0.x + a0.y * u0.y + a0.z * u0.z + a0.w * u0.w
         + a1.x * u1.x + a1.y * u1.y + a1.z * u1.z + a1.w * u1.w;
}

__global__ __launch_bounds__(BLOCK, 4) void mrn_loss_kernel(
    const float* __restrict__ wp,   // (C, D) = (1000, 512)
    const float* __restrict__ wst,  // (C, D)
    const float* __restrict__ feats,// (N, D)
    const float* __restrict__ ys,   // (N,)
    const int*   __restrict__ seg,  // (N,)
    float* __restrict__ blockout,   // per-block partials (d_ws) or null
    float* __restrict__ out,        // atomic fallback target
    int N)
{
    const int tid      = blockIdx.x * BLOCK + threadIdx.x;
    const int nthreads = GRID * BLOCK;

    float acc_a = 0.0f;
    float acc_b = 0.0f;

    // ---- Part 1: reg_loss = sum((wp - wst)^2); warms wp into every XCD L2.
    {
        const int REG4 = (1000 * 512) / 4;
        const vf4* wp4 = (const vf4*)wp;
        const vf4* ws4 = (const vf4*)wst;
        for (int i = tid; i < REG4; i += nthreads) {
            vf4 a = wp4[i];
            vf4 b = ws4[i];
            vf4 d = a - b;
            acc_a += d.x * d.x + d.y * d.y + d.z * d.z + d.w * d.w;
        }
    }

    // ---- Part 2: -sum_n y_n * <feats_n, wp[seg_n]>
    // One wave per CHUNK=49 consecutive samples (98KB contiguous feats stream).
    {
        const int lane = threadIdx.x & 63;
        const int wave = __builtin_amdgcn_readfirstlane(tid >> 6);

        for (int base = wave * CHUNK; base < N; base += NWAVES * CHUNK) {
            const int cnt = min(CHUNK, N - base);

            // Coalesced preload of this chunk's seg/ys (one transaction each).
            int   myseg = 0;
            float myy   = 0.0f;
            if (lane < cnt) {
                myseg = seg[base + lane];
                myy   = ys[base + lane];
            }

            const vf4* f4 = (const vf4*)feats + (size_t)base * 128;

            if (cnt == CHUNK) {
                #pragma unroll 3
                for (int j = 0; j < CHUNK; ++j) {
                    const int   c = __builtin_amdgcn_readlane(myseg, j);
                    const float y = __int_as_float(
                        __builtin_amdgcn_readlane(__float_as_int(myy), j));

                    const vf4* fr = f4 + (size_t)j * 128;
                    const vf4* wr = (const vf4*)(wp + (size_t)c * 512);

                    vf4 a0 = __builtin_nontemporal_load(fr + lane);
                    vf4 a1 = __builtin_nontemporal_load(fr + lane + 64);
                    vf4 u0 = wr[lane];
                    vf4 u1 = wr[lane + 64];

                    const float d = dot8(a0, a1, u0, u1);
                    if (j & 1) acc_b -= y * d;
                    else       acc_a -= y * d;
                }
            } else {
                for (int j = 0; j < cnt; ++j) {
                    const int   c = __builtin_amdgcn_readlane(myseg, j);
                    const float y = __int_as_float(
                        __builtin_amdgcn_readlane(__float_as_int(myy), j));
                    const vf4* fr = f4 + (size_t)j * 128;
                    const vf4* wr = (const vf4*)(wp + (size_t)c * 512);
                    vf4 a0 = __builtin_nontemporal_load(fr + lane);
                    vf4 a1 = __builtin_nontemporal_load(fr + lane + 64);
                    vf4 u0 = wr[lane];
                    vf4 u1 = wr[lane + 64];
                    acc_a -= y * dot8(a0, a1, u0, u1);
                }
            }
        }
    }

    // ---- Reduce: shuffle within wave, LDS across waves, one store per block.
    float acc = acc_a + acc_b;
    for (int off = 32; off > 0; off >>= 1)
        acc += __shfl_down(acc, off, 64);

    __shared__ float sacc[BLOCK / 64];
    const int lane = threadIdx.x & 63;
    const int wid  = threadIdx.x >> 6;
    if (lane == 0) sacc[wid] = acc;
    __syncthreads();

    if (threadIdx.x == 0) {
        float b = sacc[0] + sacc[1] + sacc[2] + sacc[3];
        if (blockout) blockout[blockIdx.x] = b;
        else          atomicAdd(out, b);
    }
}

extern "C" void kernel_launch(void* const* d_in, const int* in_sizes, int n_in,
                              void* d_out, int out_size, void* d_ws, size_t ws_size,
                              hipStream_t stream) {
    const float* wp    = (const float*)d_in[0];
    const float* wst   = (const float*)d_in[1];
    const float* feats = (const float*)d_in[2];
    const float* ys    = (const float*)d_in[3];
    const int*   seg   = (const int*)d_in[4];
    float* out = (float*)d_out;

    const int N = in_sizes[3];   // 200000 samples

    if (ws_size >= GRID * sizeof(float)) {
        float* part = (float*)d_ws;
        mrn_loss_kernel<<<GRID, BLOCK, 0, stream>>>(wp, wst, feats, ys, seg,
                                                    part, nullptr, N);
        final_reduce<<<1, 256, 0, stream>>>(part, out, (float)N);
    } else {
        init_out<<<1, 1, 0, stream>>>(out, (float)N);
        mrn_loss_kernel<<<GRID, BLOCK, 0, stream>>>(wp, wst, feats, ys, seg,
                                                    nullptr, out, N);
    }
}